// Round 15
// baseline (159.555 us; speedup 1.0000x reference)
//
#include <hip/hip_runtime.h>
#include <math.h>

#define Bb   4
#define Cc   256
#define Hh   48
#define Ww   48
#define NNp  2304          // H*W
#define Rr   9216          // B*N
#define NHd  4
#define QKVC 512
#define EPSf 1e-3f

typedef unsigned int   u32;
typedef unsigned short u16;
typedef __attribute__((ext_vector_type(8))) __bf16 bf16x8;
typedef __attribute__((ext_vector_type(4))) float  f32x4;

#if __has_builtin(__builtin_amdgcn_exp2f)
#define EXP2F(x) __builtin_amdgcn_exp2f(x)
#else
#define EXP2F(x) __expf((x) * 0.6931471805599453f)
#endif

__device__ __forceinline__ u16 f2bf(float f) {
    u32 u = __float_as_uint(f);
    u = (u + 0x7fffu + ((u >> 16) & 1u)) >> 16;
    return (u16)u;
}
__device__ __forceinline__ float bf2f(u16 h) {
    return __uint_as_float((u32)h << 16);
}
__device__ __forceinline__ u32 pk2bf(float a, float b) {
    union { __bf16 h; u16 u; } ua, ub;
    ua.h = (__bf16)a; ub.h = (__bf16)b;
    return (u32)ua.u | ((u32)ub.u << 16);
}
__device__ __forceinline__ void gload16(const void* gsrc, void* ldst) {
    __builtin_amdgcn_global_load_lds(
        (const __attribute__((address_space(1))) u32*)gsrc,
        (__attribute__((address_space(3))) u32*)ldst, 16, 0, 0);
}

// ---------------------------------------------------------------------------
// Fused prep: blocks 0..383 = weight prep (4 oc rows each, 1536 total);
// blocks 384..959 = x transpose (b,c,n) fp32 -> Xt [(b,n)][256] bf16.
// ---------------------------------------------------------------------------
__global__ __launch_bounds__(256)
void prep_fused(const float* __restrict__ W0, const float* __restrict__ g0, const float* __restrict__ b0, const float* __restrict__ m0, const float* __restrict__ v0, u16* __restrict__ Wb0, float* __restrict__ bi0,
                const float* __restrict__ W1, const float* __restrict__ g1, const float* __restrict__ b1, const float* __restrict__ m1, const float* __restrict__ v1, u16* __restrict__ Wb1, float* __restrict__ bi1,
                const float* __restrict__ W2, const float* __restrict__ g2, const float* __restrict__ b2, const float* __restrict__ m2, const float* __restrict__ v2, u16* __restrict__ Wb2, float* __restrict__ bi2,
                const float* __restrict__ W3, const float* __restrict__ g3, const float* __restrict__ b3, const float* __restrict__ m3, const float* __restrict__ v3, u16* __restrict__ Wb3, float* __restrict__ bi3,
                const float* __restrict__ x, u16* __restrict__ Xt)
{
    const int bid = blockIdx.x;
    const int tid = threadIdx.x;
    if (bid < 384) {
        const int row = bid * 4 + (tid >> 6);   // 0..1535
        const int lane = tid & 63;
        const float *W, *gp, *bp, *mp, *vp;
        u16* Wb; float* bias;
        int K = 256, oc;
        float c = 1.f;
        if (row < 512) {
            oc = row; W = W0; gp = g0; bp = b0; mp = m0; vp = v0; Wb = Wb0; bias = bi0;
            if ((oc & 127) < 32) c = 0.17677669529663687f * 1.4426950408889634f;
        } else if (row < 768) {
            oc = row - 512; W = W1; gp = g1; bp = b1; mp = m1; vp = v1; Wb = Wb1; bias = bi1;
        } else if (row < 1280) {
            oc = row - 768; W = W2; gp = g2; bp = b2; mp = m2; vp = v2; Wb = Wb2; bias = bi2;
        } else {
            oc = row - 1280; W = W3; gp = g3; bp = b3; mp = m3; vp = v3; Wb = Wb3; bias = bi3;
            K = 512;
        }
        const float s = gp[oc] * rsqrtf(vp[oc] + EPSf);
        if (lane == 0) bias[oc] = (bp[oc] - mp[oc] * s) * c;
        const float sc = s * c;
        for (int k0 = lane * 4; k0 < K; k0 += 256) {
            const float4 w = *(const float4*)(W + (size_t)oc * K + k0);
            u32 lo = (u32)f2bf(w.x * sc) | ((u32)f2bf(w.y * sc) << 16);
            u32 hi = (u32)f2bf(w.z * sc) | ((u32)f2bf(w.w * sc) << 16);
            *(uint2*)(Wb + (size_t)oc * K + k0) = make_uint2(lo, hi);
        }
        return;
    }
    // ---- cvt_x part ----
    const int cb = bid - 384;          // 0..575
    const int b  = cb / 144;
    const int rm = cb - b * 144;
    const int c0 = (rm / 36) * 64;
    const int n0 = (rm % 36) * 64;
    __shared__ float tile[64][65];
    {
        const int n = tid & 63, cl = tid >> 6;
        #pragma unroll
        for (int cc = 0; cc < 16; ++cc) {
            const int c = cc * 4 + cl;
            tile[c][n] = x[((size_t)b * Cc + c0 + c) * NNp + n0 + n];
        }
    }
    __syncthreads();
    {
        const int n = tid >> 2, q = tid & 3;
        #pragma unroll
        for (int j = 0; j < 2; ++j) {
            const int ch = q * 2 + j, c = ch * 8;
            u32 w[4];
            #pragma unroll
            for (int e = 0; e < 4; ++e)
                w[e] = (u32)f2bf(tile[c + 2*e][n]) | ((u32)f2bf(tile[c + 2*e + 1][n]) << 16);
            *(uint4*)(Xt + ((size_t)b * NNp + n0 + n) * Cc + c0 + c)
                = make_uint4(w[0], w[1], w[2], w[3]);
        }
    }
}

// ---------------------------------------------------------------------------
// MFMA GEMM, 64x64 tiles (BK=32), 4 waves, dbuf prefetch.
// MODE 0: bf16 out (qkv) + FUSED V-transpose into Vb for v-channel blocks
// MODE 1: +resid, fp32+bf16 out  MODE 2: SiLU bf16  MODE 3: +resid fp32
// ---------------------------------------------------------------------------
template<int MODE>
__global__ __launch_bounds__(256)
void gemm64(const u16* __restrict__ A, const u16* __restrict__ Bx,
            const float* __restrict__ bias, const float* __restrict__ resid,
            float* __restrict__ Yf, u16* __restrict__ Yt, u16* __restrict__ Vb,
            int M, int K)
{
    const int r0 = blockIdx.x * 64;
    const int m0 = blockIdx.y * 64;
    const int tid = threadIdx.x;
    const int lane = tid & 63, wid = tid >> 6;
    const int g = lane >> 4, i16 = lane & 15;

    // unified 16 KB staging block: [A/B][dbuf][kchunk][row][8]
    __shared__ __align__(16) u16 smem[2][2][4][64][8];

    f32x4 acc[4];
    #pragma unroll
    for (int j = 0; j < 4; ++j) acc[j] = (f32x4){0.f, 0.f, 0.f, 0.f};

    gload16(A + (size_t)(m0 + (tid & 63)) * K + (tid >> 6) * 8,
            &smem[0][0][0][0][0] + (size_t)tid * 8);
    gload16(Bx + (size_t)(r0 + (tid & 63)) * K + (tid >> 6) * 8,
            &smem[1][0][0][0][0] + (size_t)tid * 8);
    __syncthreads();

    int buf = 0;
    for (int k0 = 0; k0 < K; k0 += 32) {
        if (k0 + 32 < K) {
            const int kn = k0 + 32;
            gload16(A + (size_t)(m0 + (tid & 63)) * K + kn + (tid >> 6) * 8,
                    &smem[0][buf ^ 1][0][0][0] + (size_t)tid * 8);
            gload16(Bx + (size_t)(r0 + (tid & 63)) * K + kn + (tid >> 6) * 8,
                    &smem[1][buf ^ 1][0][0][0] + (size_t)tid * 8);
        }
        const bf16x8 af = *(const bf16x8*)&smem[0][buf][g][wid * 16 + i16][0];
        bf16x8 bf[4];
        #pragma unroll
        for (int bo = 0; bo < 4; ++bo)
            bf[bo] = *(const bf16x8*)&smem[1][buf][g][bo * 16 + i16][0];
        __builtin_amdgcn_s_setprio(1);
        #pragma unroll
        for (int bo = 0; bo < 4; ++bo)
            acc[bo] = __builtin_amdgcn_mfma_f32_16x16x32_bf16(af, bf[bo], acc[bo], 0, 0, 0);
        __builtin_amdgcn_s_setprio(0);
        __syncthreads();
        buf ^= 1;
    }

    const int b  = r0 / NNp;
    const int nb = r0 - b * NNp;
    const int oc0 = m0 + wid * 16 + g * 4;
    const float4 t4 = *(const float4*)(bias + oc0);
    const bool vblk = (MODE == 0) && (m0 & 64);     // v-channel block of qkv
    u16 (*vt)[72] = (u16(*)[72])&smem[0][0][0][0][0];   // 9.2 KB alias (smem dead)

    #pragma unroll
    for (int bo = 0; bo < 4; ++bo) {
        const int nloc = bo * 16 + i16;
        float y[4];
        y[0] = acc[bo][0] + t4.x;  y[1] = acc[bo][1] + t4.y;
        y[2] = acc[bo][2] + t4.z;  y[3] = acc[bo][3] + t4.w;
        if (MODE == 1 || MODE == 3) {
            const int n = nb + nloc;
            const size_t base = ((size_t)b * M + oc0) * NNp + n;
            #pragma unroll
            for (int r = 0; r < 4; ++r) {
                y[r] += resid[base + (size_t)r * NNp];
                Yf[base + (size_t)r * NNp] = y[r];
            }
        }
        if (MODE == 2) {
            #pragma unroll
            for (int r = 0; r < 4; ++r) y[r] = y[r] / (1.f + __expf(-y[r]));
        }
        if (MODE != 3) {
            const uint2 pk = make_uint2(pk2bf(y[0], y[1]), pk2bf(y[2], y[3]));
            *(uint2*)(Yt + (size_t)(r0 + nloc) * M + oc0) = pk;
            if (vblk) *(uint2*)&vt[nloc][wid * 16 + g * 4] = pk;   // vt[n][d]
        }
    }

    if (vblk) {     // block-uniform condition
        __syncthreads();
        const int h  = m0 >> 7;
        const int bh = b * NHd + h;
        const int d  = tid >> 2, mq = tid & 3;
        #pragma unroll
        for (int j = 0; j < 2; ++j) {
            const int mc = mq * 2 + j;
            u32 w[4];
            #pragma unroll
            for (int e = 0; e < 4; ++e)
                w[e] = (u32)vt[mc * 8 + 2*e][d] | ((u32)vt[mc * 8 + 2*e + 1][d] << 16);
            *(uint4*)(Vb + ((size_t)bh * 64 + d) * NNp + nb + mc * 8)
                = make_uint4(w[0], w[1], w[2], w[3]);
        }
    }
}

// ---------------------------------------------------------------------------
// pe precompute: PEb[(b,n)][c] = BN(dwconv3x3(v)) (bf16), v from Yt.
// ---------------------------------------------------------------------------
__global__ __launch_bounds__(256)
void pe_pre(const u16* __restrict__ Yt, const float* __restrict__ pw,
            const float* __restrict__ gg, const float* __restrict__ bb,
            const float* __restrict__ mm, const float* __restrict__ vv,
            u16* __restrict__ PEb)
{
    const int tid = threadIdx.x;
    const int h = blockIdx.y, b = blockIdx.z;
    const int p = blockIdx.x * 32 + (tid >> 3);
    const int ch = tid & 7;
    const int c0 = h * 64 + ch * 8;
    const int yy = p / Ww, xx = p - yy * Ww;

    float acc[8];
    #pragma unroll
    for (int j = 0; j < 8; ++j) acc[j] = 0.f;

    #pragma unroll
    for (int dy = -1; dy <= 1; ++dy) {
        const int Y = yy + dy;
        if (Y < 0 || Y >= Hh) continue;
        #pragma unroll
        for (int dx = -1; dx <= 1; ++dx) {
            const int X = xx + dx;
            if (X < 0 || X >= Ww) continue;
            const uint4 raw = *(const uint4*)(Yt +
                ((size_t)b * NNp + Y * Ww + X) * QKVC + h * 128 + 64 + ch * 8);
            const u32* rw = (const u32*)&raw;
            #pragma unroll
            for (int j = 0; j < 8; ++j) {
                const u16 hv = (u16)(rw[j >> 1] >> (16 * (j & 1)));
                acc[j] += pw[(size_t)(c0 + j) * 9 + (dy + 1) * 3 + (dx + 1)] * bf2f(hv);
            }
        }
    }

    u32 res[4];
    #pragma unroll
    for (int e = 0; e < 4; ++e) {
        const int j0 = 2 * e, j1 = 2 * e + 1;
        const float s0 = gg[c0 + j0] * rsqrtf(vv[c0 + j0] + EPSf);
        const float s1 = gg[c0 + j1] * rsqrtf(vv[c0 + j1] + EPSf);
        res[e] = pk2bf(acc[j0] * s0 + (bb[c0 + j0] - mm[c0 + j0] * s0),
                       acc[j1] * s1 + (bb[c0 + j1] - mm[c0 + j1] * s1));
    }
    *(uint4*)(PEb + ((size_t)b * NNp + p) * Cc + c0) = make_uint4(res[0], res[1], res[2], res[3]);
}

// ---------------------------------------------------------------------------
// MFMA flash attention v10: R14 structure (4 waves, QBLK=64, KVBLK=64) with
// PAIRED-TILE staging: two 64-key tiles per buffer flip, one barrier per pair
// (36 -> 18 barrier+drain events). LDS 57 KB -> 2 WG/CU (grid-cap unchanged).
// Lane-local softmax, defer-max, ones-MFMA l, XCD-swizzled grid 576, PEb add.
// ---------------------------------------------------------------------------
__global__ __launch_bounds__(256)
void attn_mfma(const u16* __restrict__ Yt, const u16* __restrict__ Vb,
               const u16* __restrict__ PEb, u16* __restrict__ Ot)
{
    __shared__ __align__(16) u16 Klds[2][2][4][64][8];    // 16 KB [buf][sub]
    __shared__ __align__(16) u16 Vlds[2][2][64][8][8];    // 32 KB [buf][sub]
    __shared__ __align__(16) u32 Plds[4][16][36];         // 9.2 KB

    const int tid  = threadIdx.x;
    const int wid  = tid >> 6;       // 0..3
    const int lane = tid & 63;
    const int g    = lane >> 4;
    const int i16  = lane & 15;

    // XCD-aware bijective swizzle: 576 WGs = 8 XCDs x 72
    const int wg  = blockIdx.x;
    const int swz = (wg & 7) * 72 + (wg >> 3);
    const int xq  = swz % 36;        // 64-query tile
    const int bh  = swz / 36;
    const int h   = bh & 3, b = bh >> 2;

    const size_t bG = (size_t)b * NNp;
    const u16* Vg = Vb + (size_t)bh * 64 * NNp;

    const int nq = xq * 64 + wid * 16 + i16;
    const bf16x8 qfrag = *(const bf16x8*)(Yt + (bG + nq) * QKVC + h * 128 + g * 8);

    bf16x8 ones;
    { uint4 ov = make_uint4(0x3f803f80u, 0x3f803f80u, 0x3f803f80u, 0x3f803f80u);
      ones = *(bf16x8*)&ov; }

    const f32x4 zero = {0.f, 0.f, 0.f, 0.f};
    f32x4 oacc[4];
    f32x4 lacc = zero;
    #pragma unroll
    for (int d = 0; d < 4; ++d) oacc[d] = zero;
    float m_run = -1e30f;

    // stage pair 0 (tiles 0 and 1): per sub, K 1 load/thread + V 2 loads/thread
    #pragma unroll
    for (int sub = 0; sub < 2; ++sub) {
        const int m0 = sub * 64;
        gload16(Yt + (bG + m0 + (tid & 63)) * QKVC + h * 128 + 32 + (tid >> 6) * 8,
                (u16*)&Klds[0][sub][0][0][0] + (size_t)tid * 8);
        #pragma unroll
        for (int ii = 0; ii < 2; ++ii) {
            const int idx = ii * 256 + tid;
            const int d = idx >> 3, cp = idx & 7;
            gload16(Vg + (size_t)d * NNp + m0 + (cp ^ (d & 7)) * 8,
                    (u16*)&Vlds[0][sub][0][0][0] + (size_t)idx * 8);
        }
    }
    __syncthreads();

    int buf = 0;
    for (int p = 0; p < 18; ++p) {
        if (p < 17) {       // prefetch pair p+1 (tiles 2p+2, 2p+3)
            #pragma unroll
            for (int sub = 0; sub < 2; ++sub) {
                const int m0 = (2 * p + 2 + sub) * 64;
                gload16(Yt + (bG + m0 + (tid & 63)) * QKVC + h * 128 + 32 + (tid >> 6) * 8,
                        (u16*)&Klds[buf ^ 1][sub][0][0][0] + (size_t)tid * 8);
                #pragma unroll
                for (int ii = 0; ii < 2; ++ii) {
                    const int idx = ii * 256 + tid;
                    const int d = idx >> 3, cp = idx & 7;
                    gload16(Vg + (size_t)d * NNp + m0 + (cp ^ (d & 7)) * 8,
                            (u16*)&Vlds[buf ^ 1][sub][0][0][0] + (size_t)idx * 8);
                }
            }
        }

        #pragma unroll
        for (int sub = 0; sub < 2; ++sub) {
            // ---- S^T = K Q^T ----
            f32x4 sac[4];
            __builtin_amdgcn_s_setprio(1);
            #pragma unroll
            for (int j = 0; j < 4; ++j) {
                const bf16x8 kf = *(const bf16x8*)&Klds[buf][sub][g][16 * j + i16][0];
                sac[j] = __builtin_amdgcn_mfma_f32_16x16x32_bf16(kf, qfrag, zero, 0, 0, 0);
            }
            __builtin_amdgcn_s_setprio(0);

            // ---- lane-local online softmax (log2 domain) ----
            float pm = sac[0][0];
            #pragma unroll
            for (int j = 0; j < 4; ++j)
                #pragma unroll
                for (int r = 0; r < 4; ++r) pm = fmaxf(pm, sac[j][r]);
            pm = fmaxf(pm, __shfl_xor(pm, 16));
            pm = fmaxf(pm, __shfl_xor(pm, 32));

            if (!__all(pm <= m_run + 8.f)) {        // defer-max
                const float mn = fmaxf(m_run, pm);
                const float fc = EXP2F(m_run - mn);
                m_run = mn;
                lacc[0] *= fc; lacc[1] *= fc; lacc[2] *= fc; lacc[3] *= fc;
                #pragma unroll
                for (int d = 0; d < 4; ++d) {
                    oacc[d][0] *= fc; oacc[d][1] *= fc;
                    oacc[d][2] *= fc; oacc[d][3] *= fc;
                }
            }

            // ---- P -> per-wave LDS row [q=i16] ----
            {
                u32* prow = &Plds[wid][i16][0];
                #pragma unroll
                for (int j = 0; j < 4; ++j) {
                    const float p0 = EXP2F(sac[j][0] - m_run);
                    const float p1 = EXP2F(sac[j][1] - m_run);
                    const float p2 = EXP2F(sac[j][2] - m_run);
                    const float p3 = EXP2F(sac[j][3] - m_run);
                    *(uint2*)&prow[8 * j + 2 * g] = make_uint2(pk2bf(p0, p1), pk2bf(p2, p3));
                }
            }

            // ---- O += V P ; l += ones P ----
            const int d7 = i16 & 7;
            __builtin_amdgcn_s_setprio(1);
            #pragma unroll
            for (int s = 0; s < 2; ++s) {
                const bf16x8 pf = *(const bf16x8*)&Plds[wid][i16][16 * s + 4 * g];
                lacc = __builtin_amdgcn_mfma_f32_16x16x32_bf16(ones, pf, lacc, 0, 0, 0);
                #pragma unroll
                for (int db = 0; db < 4; ++db) {
                    const bf16x8 vf = *(const bf16x8*)&Vlds[buf][sub][db * 16 + i16][(4 * s + g) ^ d7][0];
                    oacc[db] = __builtin_amdgcn_mfma_f32_16x16x32_bf16(vf, pf, oacc[db], 0, 0, 0);
                }
            }
            __builtin_amdgcn_s_setprio(0);
        }

        __syncthreads();
        buf ^= 1;
    }

    // epilogue: lane-local 1/l, add PEb, store O[d][q=i16]
    const float linv = 1.f / lacc[0];
    const u16* pb = PEb + (bG + nq) * Cc + h * 64;
    u16* ob = Ot + (bG + nq) * Cc + h * 64;
    #pragma unroll
    for (int db = 0; db < 4; ++db) {
        const uint2 pv = *(const uint2*)(pb + db * 16 + g * 4);
        const float y0 = oacc[db][0] * linv + bf2f((u16)(pv.x & 0xffff));
        const float y1 = oacc[db][1] * linv + bf2f((u16)(pv.x >> 16));
        const float y2 = oacc[db][2] * linv + bf2f((u16)(pv.y & 0xffff));
        const float y3 = oacc[db][3] * linv + bf2f((u16)(pv.y >> 16));
        *(uint2*)(ob + db * 16 + g * 4) = make_uint2(pk2bf(y0, y1), pk2bf(y2, y3));
    }
}

// ---------------------------------------------------------------------------
extern "C" void kernel_launch(void* const* d_in, const int* in_sizes, int n_in,
                              void* d_out, int out_size, void* d_ws, size_t ws_size,
                              hipStream_t stream)
{
    const float* x      = (const float*)d_in[0];
    const float* qkv_w  = (const float*)d_in[1];
    const float* qkv_g  = (const float*)d_in[2];
    const float* qkv_b  = (const float*)d_in[3];
    const float* qkv_m  = (const float*)d_in[4];
    const float* qkv_v  = (const float*)d_in[5];
    const float* pe_w   = (const float*)d_in[6];
    const float* pe_g   = (const float*)d_in[7];
    const float* pe_b   = (const float*)d_in[8];
    const float* pe_m   = (const float*)d_in[9];
    const float* pe_v   = (const float*)d_in[10];
    const float* proj_w = (const float*)d_in[11];
    const float* proj_g = (const float*)d_in[12];
    const float* proj_b = (const float*)d_in[13];
    const float* proj_m = (const float*)d_in[14];
    const float* proj_v = (const float*)d_in[15];
    const float* f1_w   = (const float*)d_in[16];
    const float* f1_g   = (const float*)d_in[17];
    const float* f1_b   = (const float*)d_in[18];
    const float* f1_m   = (const float*)d_in[19];
    const float* f1_v   = (const float*)d_in[20];
    const float* f2_w   = (const float*)d_in[21];
    const float* f2_g   = (const float*)d_in[22];
    const float* f2_b   = (const float*)d_in[23];
    const float* f2_m   = (const float*)d_in[24];
    const float* f2_v   = (const float*)d_in[25];

    char* wsb = (char*)d_ws;
    u16*   Yt   = (u16*)(wsb);                      //  9,437,184 B (alias Ft)
    u16*   Xt   = (u16*)(wsb + 9437184);            //  4,718,592 B (alias X1t)
    u16*   Vb   = (u16*)(wsb + 14155776);           //  4,718,592 B
    u16*   Ot   = (u16*)(wsb + 18874368);           //  4,718,592 B
    float* x1f  = (float*)(wsb + 23592960);         //  9,437,184 B
    u16*   PEb  = (u16*)(wsb + 23592960);           //  4,718,592 B (dead once proj writes x1f)
    u16*   Wq   = (u16*)(wsb + 33030144);
    u16*   Wp   = (u16*)(wsb + 33292288);
    u16*   W1   = (u16*)(wsb + 33423360);
    u16*   W2   = (u16*)(wsb + 33685504);
    float* biq  = (float*)(wsb + 33947648);
    float* bip  = (float*)(wsb + 33949696);
    float* bi1  = (float*)(wsb + 33950720);
    float* bi2  = (float*)(wsb + 33952768);
    u16*   Ft   = Yt;
    u16*   X1t  = Xt;
    float* out  = (float*)d_out;

    prep_fused<<<dim3(960), dim3(256), 0, stream>>>(
        qkv_w, qkv_g, qkv_b, qkv_m, qkv_v, Wq, biq,
        proj_w, proj_g, proj_b, proj_m, proj_v, Wp, bip,
        f1_w, f1_g, f1_b, f1_m, f1_v, W1, bi1,
        f2_w, f2_g, f2_b, f2_m, f2_v, W2, bi2,
        x, Xt);

    // qkv = fold(BN) o conv1x1, with fused V-transpose into Vb
    gemm64<0><<<dim3(144, 8), dim3(256), 0, stream>>>(
        Wq, Xt, biq, nullptr, nullptr, Yt, Vb, QKVC, 256);

    // pe precompute -> PEb
    pe_pre<<<dim3(72, 4, 4), dim3(256), 0, stream>>>(
        Yt, pe_w, pe_g, pe_b, pe_m, pe_v, PEb);

    // attention v10 (paired-tile, 4-wave) -> Ot (adds PEb in epilogue)
    attn_mfma<<<dim3(576), dim3(256), 0, stream>>>(Yt, Vb, PEb, Ot);

    // proj (+x residual) -> x1f fp32 + X1t bf16
    gemm64<1><<<dim3(144, 4), dim3(256), 0, stream>>>(
        Wp, Ot, bip, x, x1f, X1t, nullptr, Cc, 256);

    // f1 + SiLU -> Ft bf16
    gemm64<2><<<dim3(144, 8), dim3(256), 0, stream>>>(
        W1, X1t, bi1, nullptr, nullptr, Ft, nullptr, QKVC, 256);

    // f2 (+x1f residual) -> out fp32
    gemm64<3><<<dim3(144, 4), dim3(256), 0, stream>>>(
        W2, Ft, bi2, x1f, out, nullptr, nullptr, Cc, 512);
}

// Round 16
// 140.147 us; speedup vs baseline: 1.1385x; 1.1385x over previous
//
#include <hip/hip_runtime.h>
#include <math.h>

#define Bb   4
#define Cc   256
#define Hh   48
#define Ww   48
#define NNp  2304          // H*W
#define Rr   9216          // B*N
#define NHd  4
#define QKVC 512
#define EPSf 1e-3f

typedef unsigned int   u32;
typedef unsigned short u16;
typedef __attribute__((ext_vector_type(8))) __bf16 bf16x8;
typedef __attribute__((ext_vector_type(4))) float  f32x4;

#if __has_builtin(__builtin_amdgcn_exp2f)
#define EXP2F(x) __builtin_amdgcn_exp2f(x)
#else
#define EXP2F(x) __expf((x) * 0.6931471805599453f)
#endif

__device__ __forceinline__ u16 f2bf(float f) {
    u32 u = __float_as_uint(f);
    u = (u + 0x7fffu + ((u >> 16) & 1u)) >> 16;
    return (u16)u;
}
__device__ __forceinline__ float bf2f(u16 h) {
    return __uint_as_float((u32)h << 16);
}
__device__ __forceinline__ u32 pk2bf(float a, float b) {
    union { __bf16 h; u16 u; } ua, ub;
    ua.h = (__bf16)a; ub.h = (__bf16)b;
    return (u32)ua.u | ((u32)ub.u << 16);
}
__device__ __forceinline__ void gload16(const void* gsrc, void* ldst) {
    __builtin_amdgcn_global_load_lds(
        (const __attribute__((address_space(1))) u32*)gsrc,
        (__attribute__((address_space(3))) u32*)ldst, 16, 0, 0);
}

// ---------------------------------------------------------------------------
// Fused prep: blocks 0..383 = weight prep (4 oc rows each, 1536 total);
// blocks 384..959 = x transpose (b,c,n) fp32 -> Xt [(b,n)][256] bf16.
// ---------------------------------------------------------------------------
__global__ __launch_bounds__(256)
void prep_fused(const float* __restrict__ W0, const float* __restrict__ g0, const float* __restrict__ b0, const float* __restrict__ m0, const float* __restrict__ v0, u16* __restrict__ Wb0, float* __restrict__ bi0,
                const float* __restrict__ W1, const float* __restrict__ g1, const float* __restrict__ b1, const float* __restrict__ m1, const float* __restrict__ v1, u16* __restrict__ Wb1, float* __restrict__ bi1,
                const float* __restrict__ W2, const float* __restrict__ g2, const float* __restrict__ b2, const float* __restrict__ m2, const float* __restrict__ v2, u16* __restrict__ Wb2, float* __restrict__ bi2,
                const float* __restrict__ W3, const float* __restrict__ g3, const float* __restrict__ b3, const float* __restrict__ m3, const float* __restrict__ v3, u16* __restrict__ Wb3, float* __restrict__ bi3,
                const float* __restrict__ x, u16* __restrict__ Xt)
{
    const int bid = blockIdx.x;
    const int tid = threadIdx.x;
    if (bid < 384) {
        const int row = bid * 4 + (tid >> 6);   // 0..1535
        const int lane = tid & 63;
        const float *W, *gp, *bp, *mp, *vp;
        u16* Wb; float* bias;
        int K = 256, oc;
        float c = 1.f;
        if (row < 512) {
            oc = row; W = W0; gp = g0; bp = b0; mp = m0; vp = v0; Wb = Wb0; bias = bi0;
            if ((oc & 127) < 32) c = 0.17677669529663687f * 1.4426950408889634f;
        } else if (row < 768) {
            oc = row - 512; W = W1; gp = g1; bp = b1; mp = m1; vp = v1; Wb = Wb1; bias = bi1;
        } else if (row < 1280) {
            oc = row - 768; W = W2; gp = g2; bp = b2; mp = m2; vp = v2; Wb = Wb2; bias = bi2;
        } else {
            oc = row - 1280; W = W3; gp = g3; bp = b3; mp = m3; vp = v3; Wb = Wb3; bias = bi3;
            K = 512;
        }
        const float s = gp[oc] * rsqrtf(vp[oc] + EPSf);
        if (lane == 0) bias[oc] = (bp[oc] - mp[oc] * s) * c;
        const float sc = s * c;
        for (int k0 = lane * 4; k0 < K; k0 += 256) {
            const float4 w = *(const float4*)(W + (size_t)oc * K + k0);
            u32 lo = (u32)f2bf(w.x * sc) | ((u32)f2bf(w.y * sc) << 16);
            u32 hi = (u32)f2bf(w.z * sc) | ((u32)f2bf(w.w * sc) << 16);
            *(uint2*)(Wb + (size_t)oc * K + k0) = make_uint2(lo, hi);
        }
        return;
    }
    // ---- cvt_x part ----
    const int cb = bid - 384;          // 0..575
    const int b  = cb / 144;
    const int rm = cb - b * 144;
    const int c0 = (rm / 36) * 64;
    const int n0 = (rm % 36) * 64;
    __shared__ float tile[64][65];
    {
        const int n = tid & 63, cl = tid >> 6;
        #pragma unroll
        for (int cc = 0; cc < 16; ++cc) {
            const int c = cc * 4 + cl;
            tile[c][n] = x[((size_t)b * Cc + c0 + c) * NNp + n0 + n];
        }
    }
    __syncthreads();
    {
        const int n = tid >> 2, q = tid & 3;
        #pragma unroll
        for (int j = 0; j < 2; ++j) {
            const int ch = q * 2 + j, c = ch * 8;
            u32 w[4];
            #pragma unroll
            for (int e = 0; e < 4; ++e)
                w[e] = (u32)f2bf(tile[c + 2*e][n]) | ((u32)f2bf(tile[c + 2*e + 1][n]) << 16);
            *(uint4*)(Xt + ((size_t)b * NNp + n0 + n) * Cc + c0 + c)
                = make_uint4(w[0], w[1], w[2], w[3]);
        }
    }
}

// ---------------------------------------------------------------------------
// MFMA GEMM, 64x64 tiles (BK=32), 4 waves, dbuf prefetch.
// MODE 0: bf16 out (qkv) + FUSED V-transpose into Vb for v-channel blocks
// MODE 1: +resid, fp32+bf16 out  MODE 2: SiLU bf16  MODE 3: +resid fp32
// ---------------------------------------------------------------------------
template<int MODE>
__global__ __launch_bounds__(256)
void gemm64(const u16* __restrict__ A, const u16* __restrict__ Bx,
            const float* __restrict__ bias, const float* __restrict__ resid,
            float* __restrict__ Yf, u16* __restrict__ Yt, u16* __restrict__ Vb,
            int M, int K)
{
    const int r0 = blockIdx.x * 64;
    const int m0 = blockIdx.y * 64;
    const int tid = threadIdx.x;
    const int lane = tid & 63, wid = tid >> 6;
    const int g = lane >> 4, i16 = lane & 15;

    // unified 16 KB staging block: [A/B][dbuf][kchunk][row][8]
    __shared__ __align__(16) u16 smem[2][2][4][64][8];

    f32x4 acc[4];
    #pragma unroll
    for (int j = 0; j < 4; ++j) acc[j] = (f32x4){0.f, 0.f, 0.f, 0.f};

    gload16(A + (size_t)(m0 + (tid & 63)) * K + (tid >> 6) * 8,
            &smem[0][0][0][0][0] + (size_t)tid * 8);
    gload16(Bx + (size_t)(r0 + (tid & 63)) * K + (tid >> 6) * 8,
            &smem[1][0][0][0][0] + (size_t)tid * 8);
    __syncthreads();

    int buf = 0;
    for (int k0 = 0; k0 < K; k0 += 32) {
        if (k0 + 32 < K) {
            const int kn = k0 + 32;
            gload16(A + (size_t)(m0 + (tid & 63)) * K + kn + (tid >> 6) * 8,
                    &smem[0][buf ^ 1][0][0][0] + (size_t)tid * 8);
            gload16(Bx + (size_t)(r0 + (tid & 63)) * K + kn + (tid >> 6) * 8,
                    &smem[1][buf ^ 1][0][0][0] + (size_t)tid * 8);
        }
        const bf16x8 af = *(const bf16x8*)&smem[0][buf][g][wid * 16 + i16][0];
        bf16x8 bf[4];
        #pragma unroll
        for (int bo = 0; bo < 4; ++bo)
            bf[bo] = *(const bf16x8*)&smem[1][buf][g][bo * 16 + i16][0];
        __builtin_amdgcn_s_setprio(1);
        #pragma unroll
        for (int bo = 0; bo < 4; ++bo)
            acc[bo] = __builtin_amdgcn_mfma_f32_16x16x32_bf16(af, bf[bo], acc[bo], 0, 0, 0);
        __builtin_amdgcn_s_setprio(0);
        __syncthreads();
        buf ^= 1;
    }

    const int b  = r0 / NNp;
    const int nb = r0 - b * NNp;
    const int oc0 = m0 + wid * 16 + g * 4;
    const float4 t4 = *(const float4*)(bias + oc0);
    const bool vblk = (MODE == 0) && (m0 & 64);     // v-channel block of qkv
    u16 (*vt)[72] = (u16(*)[72])&smem[0][0][0][0][0];   // 9.2 KB alias (smem dead)

    #pragma unroll
    for (int bo = 0; bo < 4; ++bo) {
        const int nloc = bo * 16 + i16;
        float y[4];
        y[0] = acc[bo][0] + t4.x;  y[1] = acc[bo][1] + t4.y;
        y[2] = acc[bo][2] + t4.z;  y[3] = acc[bo][3] + t4.w;
        if (MODE == 1 || MODE == 3) {
            const int n = nb + nloc;
            const size_t base = ((size_t)b * M + oc0) * NNp + n;
            #pragma unroll
            for (int r = 0; r < 4; ++r) {
                y[r] += resid[base + (size_t)r * NNp];
                Yf[base + (size_t)r * NNp] = y[r];
            }
        }
        if (MODE == 2) {
            #pragma unroll
            for (int r = 0; r < 4; ++r) y[r] = y[r] / (1.f + __expf(-y[r]));
        }
        if (MODE != 3) {
            const uint2 pk = make_uint2(pk2bf(y[0], y[1]), pk2bf(y[2], y[3]));
            *(uint2*)(Yt + (size_t)(r0 + nloc) * M + oc0) = pk;
            if (vblk) *(uint2*)&vt[nloc][wid * 16 + g * 4] = pk;   // vt[n][d]
        }
    }

    if (vblk) {     // block-uniform condition
        __syncthreads();
        const int h  = m0 >> 7;
        const int bh = b * NHd + h;
        const int d  = tid >> 2, mq = tid & 3;
        #pragma unroll
        for (int j = 0; j < 2; ++j) {
            const int mc = mq * 2 + j;
            u32 w[4];
            #pragma unroll
            for (int e = 0; e < 4; ++e)
                w[e] = (u32)vt[mc * 8 + 2*e][d] | ((u32)vt[mc * 8 + 2*e + 1][d] << 16);
            *(uint4*)(Vb + ((size_t)bh * 64 + d) * NNp + nb + mc * 8)
                = make_uint4(w[0], w[1], w[2], w[3]);
        }
    }
}

// ---------------------------------------------------------------------------
// pe precompute: PEb[(b,n)][c] = BN(dwconv3x3(v)) (bf16), v from Yt.
// ---------------------------------------------------------------------------
__global__ __launch_bounds__(256)
void pe_pre(const u16* __restrict__ Yt, const float* __restrict__ pw,
            const float* __restrict__ gg, const float* __restrict__ bb,
            const float* __restrict__ mm, const float* __restrict__ vv,
            u16* __restrict__ PEb)
{
    const int tid = threadIdx.x;
    const int h = blockIdx.y, b = blockIdx.z;
    const int p = blockIdx.x * 32 + (tid >> 3);
    const int ch = tid & 7;
    const int c0 = h * 64 + ch * 8;
    const int yy = p / Ww, xx = p - yy * Ww;

    float acc[8];
    #pragma unroll
    for (int j = 0; j < 8; ++j) acc[j] = 0.f;

    #pragma unroll
    for (int dy = -1; dy <= 1; ++dy) {
        const int Y = yy + dy;
        if (Y < 0 || Y >= Hh) continue;
        #pragma unroll
        for (int dx = -1; dx <= 1; ++dx) {
            const int X = xx + dx;
            if (X < 0 || X >= Ww) continue;
            const uint4 raw = *(const uint4*)(Yt +
                ((size_t)b * NNp + Y * Ww + X) * QKVC + h * 128 + 64 + ch * 8);
            const u32* rw = (const u32*)&raw;
            #pragma unroll
            for (int j = 0; j < 8; ++j) {
                const u16 hv = (u16)(rw[j >> 1] >> (16 * (j & 1)));
                acc[j] += pw[(size_t)(c0 + j) * 9 + (dy + 1) * 3 + (dx + 1)] * bf2f(hv);
            }
        }
    }

    u32 res[4];
    #pragma unroll
    for (int e = 0; e < 4; ++e) {
        const int j0 = 2 * e, j1 = 2 * e + 1;
        const float s0 = gg[c0 + j0] * rsqrtf(vv[c0 + j0] + EPSf);
        const float s1 = gg[c0 + j1] * rsqrtf(vv[c0 + j1] + EPSf);
        res[e] = pk2bf(acc[j0] * s0 + (bb[c0 + j0] - mm[c0 + j0] * s0),
                       acc[j1] * s1 + (bb[c0 + j1] - mm[c0 + j1] * s1));
    }
    *(uint4*)(PEb + ((size_t)b * NNp + p) * Cc + c0) = make_uint4(res[0], res[1], res[2], res[3]);
}

// ---------------------------------------------------------------------------
// MFMA flash attention (R14-verified best): 4 waves/WG (QBLK=64), KVBLK=64,
// dbuf gload_lds staging (V pre-swizzled), lane-local softmax, defer-max,
// ones-MFMA l, XCD-swizzled grid 576. Epilogue adds PEb. LDS 33.8 KB.
// ---------------------------------------------------------------------------
__global__ __launch_bounds__(256)
void attn_mfma(const u16* __restrict__ Yt, const u16* __restrict__ Vb,
               const u16* __restrict__ PEb, u16* __restrict__ Ot)
{
    __shared__ __align__(16) u16 Klds[2][4][64][8];    //  8 KB
    __shared__ __align__(16) u16 Vlds[2][64][8][8];    // 16 KB
    __shared__ __align__(16) u32 Plds[4][16][36];      // 9.2 KB

    const int tid  = threadIdx.x;
    const int wid  = tid >> 6;       // 0..3
    const int lane = tid & 63;
    const int g    = lane >> 4;
    const int i16  = lane & 15;

    // XCD-aware bijective swizzle: 576 WGs = 8 XCDs x 72
    const int wg  = blockIdx.x;
    const int swz = (wg & 7) * 72 + (wg >> 3);
    const int xq  = swz % 36;        // 64-query tile
    const int bh  = swz / 36;
    const int h   = bh & 3, b = bh >> 2;

    const size_t bG = (size_t)b * NNp;
    const u16* Vg = Vb + (size_t)bh * 64 * NNp;

    const int nq = xq * 64 + wid * 16 + i16;
    const bf16x8 qfrag = *(const bf16x8*)(Yt + (bG + nq) * QKVC + h * 128 + g * 8);

    bf16x8 ones;
    { uint4 ov = make_uint4(0x3f803f80u, 0x3f803f80u, 0x3f803f80u, 0x3f803f80u);
      ones = *(bf16x8*)&ov; }

    const f32x4 zero = {0.f, 0.f, 0.f, 0.f};
    f32x4 oacc[4];
    f32x4 lacc = zero;
    #pragma unroll
    for (int d = 0; d < 4; ++d) oacc[d] = zero;
    float m_run = -1e30f;

    // stage tile 0: K 4KB (1 load/thread over 256), V 8KB (2 loads/thread)
    gload16(Yt + (bG + (tid & 63)) * QKVC + h * 128 + 32 + (tid >> 6) * 8,
            (u16*)&Klds[0][0][0][0] + (size_t)tid * 8);
    #pragma unroll
    for (int ii = 0; ii < 2; ++ii) {
        const int idx = ii * 256 + tid;
        const int d = idx >> 3, cp = idx & 7;
        gload16(Vg + (size_t)d * NNp + (cp ^ (d & 7)) * 8,
                (u16*)&Vlds[0][0][0][0] + (size_t)idx * 8);
    }
    __syncthreads();

    int cur = 0;
    for (int t = 0; t < 36; ++t) {
        if (t < 35) {       // prefetch next 64-key tile
            const int m0 = (t + 1) * 64;
            gload16(Yt + (bG + m0 + (tid & 63)) * QKVC + h * 128 + 32 + (tid >> 6) * 8,
                    (u16*)&Klds[cur ^ 1][0][0][0] + (size_t)tid * 8);
            #pragma unroll
            for (int ii = 0; ii < 2; ++ii) {
                const int idx = ii * 256 + tid;
                const int d = idx >> 3, cp = idx & 7;
                gload16(Vg + (size_t)d * NNp + m0 + (cp ^ (d & 7)) * 8,
                        (u16*)&Vlds[cur ^ 1][0][0][0] + (size_t)idx * 8);
            }
        }

        // ---- S^T = K Q^T ----
        f32x4 sac[4];
        __builtin_amdgcn_s_setprio(1);
        #pragma unroll
        for (int j = 0; j < 4; ++j) {
            const bf16x8 kf = *(const bf16x8*)&Klds[cur][g][16 * j + i16][0];
            sac[j] = __builtin_amdgcn_mfma_f32_16x16x32_bf16(kf, qfrag, zero, 0, 0, 0);
        }
        __builtin_amdgcn_s_setprio(0);

        // ---- lane-local online softmax (log2 domain) ----
        float pm = sac[0][0];
        #pragma unroll
        for (int j = 0; j < 4; ++j)
            #pragma unroll
            for (int r = 0; r < 4; ++r) pm = fmaxf(pm, sac[j][r]);
        pm = fmaxf(pm, __shfl_xor(pm, 16));
        pm = fmaxf(pm, __shfl_xor(pm, 32));

        if (!__all(pm <= m_run + 8.f)) {        // defer-max
            const float mn = fmaxf(m_run, pm);
            const float fc = EXP2F(m_run - mn);
            m_run = mn;
            lacc[0] *= fc; lacc[1] *= fc; lacc[2] *= fc; lacc[3] *= fc;
            #pragma unroll
            for (int d = 0; d < 4; ++d) {
                oacc[d][0] *= fc; oacc[d][1] *= fc;
                oacc[d][2] *= fc; oacc[d][3] *= fc;
            }
        }

        // ---- P -> per-wave LDS row [q=i16] ----
        {
            u32* prow = &Plds[wid][i16][0];
            #pragma unroll
            for (int j = 0; j < 4; ++j) {
                const float p0 = EXP2F(sac[j][0] - m_run);
                const float p1 = EXP2F(sac[j][1] - m_run);
                const float p2 = EXP2F(sac[j][2] - m_run);
                const float p3 = EXP2F(sac[j][3] - m_run);
                *(uint2*)&prow[8 * j + 2 * g] = make_uint2(pk2bf(p0, p1), pk2bf(p2, p3));
            }
        }

        // ---- O += V P ; l += ones P ----
        const int d7 = i16 & 7;
        __builtin_amdgcn_s_setprio(1);
        #pragma unroll
        for (int s = 0; s < 2; ++s) {
            const bf16x8 pf = *(const bf16x8*)&Plds[wid][i16][16 * s + 4 * g];
            lacc = __builtin_amdgcn_mfma_f32_16x16x32_bf16(ones, pf, lacc, 0, 0, 0);
            #pragma unroll
            for (int db = 0; db < 4; ++db) {
                const bf16x8 vf = *(const bf16x8*)&Vlds[cur][db * 16 + i16][(4 * s + g) ^ d7][0];
                oacc[db] = __builtin_amdgcn_mfma_f32_16x16x32_bf16(vf, pf, oacc[db], 0, 0, 0);
            }
        }
        __builtin_amdgcn_s_setprio(0);

        __syncthreads();
        cur ^= 1;
    }

    // epilogue: lane-local 1/l, add PEb, store O[d][q=i16]
    const float linv = 1.f / lacc[0];
    const u16* pb = PEb + (bG + nq) * Cc + h * 64;
    u16* ob = Ot + (bG + nq) * Cc + h * 64;
    #pragma unroll
    for (int db = 0; db < 4; ++db) {
        const uint2 pv = *(const uint2*)(pb + db * 16 + g * 4);
        const float y0 = oacc[db][0] * linv + bf2f((u16)(pv.x & 0xffff));
        const float y1 = oacc[db][1] * linv + bf2f((u16)(pv.x >> 16));
        const float y2 = oacc[db][2] * linv + bf2f((u16)(pv.y & 0xffff));
        const float y3 = oacc[db][3] * linv + bf2f((u16)(pv.y >> 16));
        *(uint2*)(ob + db * 16 + g * 4) = make_uint2(pk2bf(y0, y1), pk2bf(y2, y3));
    }
}

// ---------------------------------------------------------------------------
extern "C" void kernel_launch(void* const* d_in, const int* in_sizes, int n_in,
                              void* d_out, int out_size, void* d_ws, size_t ws_size,
                              hipStream_t stream)
{
    const float* x      = (const float*)d_in[0];
    const float* qkv_w  = (const float*)d_in[1];
    const float* qkv_g  = (const float*)d_in[2];
    const float* qkv_b  = (const float*)d_in[3];
    const float* qkv_m  = (const float*)d_in[4];
    const float* qkv_v  = (const float*)d_in[5];
    const float* pe_w   = (const float*)d_in[6];
    const float* pe_g   = (const float*)d_in[7];
    const float* pe_b   = (const float*)d_in[8];
    const float* pe_m   = (const float*)d_in[9];
    const float* pe_v   = (const float*)d_in[10];
    const float* proj_w = (const float*)d_in[11];
    const float* proj_g = (const float*)d_in[12];
    const float* proj_b = (const float*)d_in[13];
    const float* proj_m = (const float*)d_in[14];
    const float* proj_v = (const float*)d_in[15];
    const float* f1_w   = (const float*)d_in[16];
    const float* f1_g   = (const float*)d_in[17];
    const float* f1_b   = (const float*)d_in[18];
    const float* f1_m   = (const float*)d_in[19];
    const float* f1_v   = (const float*)d_in[20];
    const float* f2_w   = (const float*)d_in[21];
    const float* f2_g   = (const float*)d_in[22];
    const float* f2_b   = (const float*)d_in[23];
    const float* f2_m   = (const float*)d_in[24];
    const float* f2_v   = (const float*)d_in[25];

    char* wsb = (char*)d_ws;
    u16*   Yt   = (u16*)(wsb);                      //  9,437,184 B (alias Ft)
    u16*   Xt   = (u16*)(wsb + 9437184);            //  4,718,592 B (alias X1t)
    u16*   Vb   = (u16*)(wsb + 14155776);           //  4,718,592 B
    u16*   Ot   = (u16*)(wsb + 18874368);           //  4,718,592 B
    float* x1f  = (float*)(wsb + 23592960);         //  9,437,184 B
    u16*   PEb  = (u16*)(wsb + 23592960);           //  4,718,592 B (dead once proj writes x1f)
    u16*   Wq   = (u16*)(wsb + 33030144);
    u16*   Wp   = (u16*)(wsb + 33292288);
    u16*   W1   = (u16*)(wsb + 33423360);
    u16*   W2   = (u16*)(wsb + 33685504);
    float* biq  = (float*)(wsb + 33947648);
    float* bip  = (float*)(wsb + 33949696);
    float* bi1  = (float*)(wsb + 33950720);
    float* bi2  = (float*)(wsb + 33952768);
    u16*   Ft   = Yt;
    u16*   X1t  = Xt;
    float* out  = (float*)d_out;

    prep_fused<<<dim3(960), dim3(256), 0, stream>>>(
        qkv_w, qkv_g, qkv_b, qkv_m, qkv_v, Wq, biq,
        proj_w, proj_g, proj_b, proj_m, proj_v, Wp, bip,
        f1_w, f1_g, f1_b, f1_m, f1_v, W1, bi1,
        f2_w, f2_g, f2_b, f2_m, f2_v, W2, bi2,
        x, Xt);

    // qkv = fold(BN) o conv1x1, with fused V-transpose into Vb
    gemm64<0><<<dim3(144, 8), dim3(256), 0, stream>>>(
        Wq, Xt, biq, nullptr, nullptr, Yt, Vb, QKVC, 256);

    // pe precompute -> PEb
    pe_pre<<<dim3(72, 4, 4), dim3(256), 0, stream>>>(
        Yt, pe_w, pe_g, pe_b, pe_m, pe_v, PEb);

    // attention (R14-verified, 4-wave QBLK=64) -> Ot (adds PEb in epilogue)
    attn_mfma<<<dim3(576), dim3(256), 0, stream>>>(Yt, Vb, PEb, Ot);

    // proj (+x residual) -> x1f fp32 + X1t bf16
    gemm64<1><<<dim3(144, 4), dim3(256), 0, stream>>>(
        Wp, Ot, bip, x, x1f, X1t, nullptr, Cc, 256);

    // f1 + SiLU -> Ft bf16
    gemm64<2><<<dim3(144, 8), dim3(256), 0, stream>>>(
        W1, X1t, bi1, nullptr, nullptr, Ft, nullptr, QKVC, 256);

    // f2 (+x1f residual) -> out fp32
    gemm64<3><<<dim3(144, 4), dim3(256), 0, stream>>>(
        W2, Ft, bi2, x1f, out, nullptr, nullptr, Cc, 512);
}